// Round 5
// baseline (578.727 us; speedup 1.0000x reference)
//
#include <hip/hip_runtime.h>
#include <cstdint>
#include <cstddef>

typedef unsigned short u16;
typedef unsigned int u32;

typedef __bf16 bf16x8 __attribute__((ext_vector_type(8)));
typedef float f32x4 __attribute__((ext_vector_type(4)));
typedef u32 u32x4 __attribute__((ext_vector_type(4)));

__device__ inline float bf2f(u16 u) {
    union { u32 i; float f; } c; c.i = ((u32)u) << 16; return c.f;
}
__device__ inline u16 f2bf(float f) {
    union { float f; u32 i; } c; c.f = f;
    u32 u = c.i;
    return (u16)((u + 0x7fffu + ((u >> 16) & 1u)) >> 16);  // RNE
}
__device__ inline f32x4 mfma16(u32x4 a, u32x4 b, f32x4 c) {
    return __builtin_amdgcn_mfma_f32_16x16x32_bf16(
        __builtin_bit_cast(bf16x8, a), __builtin_bit_cast(bf16x8, b), c, 0, 0, 0);
}
__device__ inline u32x4 cvt8(const float* p) {
    f32x4 a = *(const f32x4*)p, b = *(const f32x4*)(p + 4);
    u32x4 v;
    v[0] = (u32)f2bf(a[0]) | ((u32)f2bf(a[1]) << 16);
    v[1] = (u32)f2bf(a[2]) | ((u32)f2bf(a[3]) << 16);
    v[2] = (u32)f2bf(b[0]) | ((u32)f2bf(b[1]) << 16);
    v[3] = (u32)f2bf(b[2]) | ((u32)f2bf(b[3]) << 16);
    return v;
}

// ===================== dtype detector (round-1 forensics: inputs fp32) ========
__global__ __launch_bounds__(64) void k_detect(const u16* __restrict__ x, u32* __restrict__ flag)
{
    const int lane = threadIdx.x;
    int cnt = 0;
#pragma unroll
    for (int i = 0; i < 4; i++) {
        u32 e = (x[lane * 4 + i] >> 7) & 0xFF;
        cnt += (e >= 115 && e <= 133) ? 1 : 0;
    }
#pragma unroll
    for (int off = 1; off < 64; off <<= 1) cnt += __shfl_xor(cnt, off);
    if (lane == 0) *flag = (cnt >= 192) ? 1u : 0u;
}

// ===================== weight transpose (unchanged, validated) ================
__global__ __launch_bounds__(256) void k_transpose_w(
    const void* __restrict__ Wq, const void* __restrict__ Wkv, const void* __restrict__ Wo,
    u16* __restrict__ WT, u16* __restrict__ WoT, const u32* __restrict__ flag)
{
    const bool isb = (*flag != 0);
    __shared__ __align__(16) u16 t[64][72];
    const int z = blockIdx.z;
    const void* src; u16* dst; int C;
    if (z == 0)      { src = Wq;  dst = WT;             C = 768;  }
    else if (z == 1) { src = Wkv; dst = WT + 768 * 768; C = 1536; }
    else             { src = Wo;  dst = WoT;            C = 768;  }
    const int c0 = blockIdx.y * 64;
    if (c0 >= C) return;
    const int k0 = blockIdx.x * 64;
    const int tid = threadIdx.x;
    const int r = tid >> 3, cc = (tid & 7) * 8;
    if (isb) {
        const u16* s = (const u16*)src;
        for (int rr = r; rr < 64; rr += 32)
            *(u32x4*)&t[rr][cc] = *(const u32x4*)(s + (size_t)(k0 + rr) * C + c0 + cc);
    } else {
        const float* s = (const float*)src;
        for (int rr = r; rr < 64; rr += 32)
            *(u32x4*)&t[rr][cc] = cvt8(s + (size_t)(k0 + rr) * C + c0 + cc);
    }
    __syncthreads();
    const int kk = (tid & 7) * 8;
    for (int ccc = tid >> 3; ccc < 64; ccc += 32) {
        __align__(16) u16 tmp[8];
#pragma unroll
        for (int s = 0; s < 8; s++) tmp[s] = t[kk + s][ccc];
        *(u32x4*)(dst + (size_t)(c0 + ccc) * 768 + k0 + kk) = *(u32x4*)tmp;
    }
}

// ===================== v transpose (unchanged, validated) =====================
__global__ __launch_bounds__(256) void k_transpose_v(
    const u16* __restrict__ v, u16* __restrict__ vt)
{
    __shared__ __align__(16) u16 t[64][72];
    const int bh = blockIdx.z;
    const int t0 = blockIdx.x * 64;
    const int tid = threadIdx.x;
    const int r = tid >> 3, cc = (tid & 7) * 8;
    for (int rr = r; rr < 64; rr += 32)
        *(u32x4*)&t[rr][cc] = *(const u32x4*)(v + ((size_t)bh * 1024 + t0 + rr) * 64 + cc);
    __syncthreads();
    const int kk = (tid & 7) * 8;
    for (int ccc = tid >> 3; ccc < 64; ccc += 32) {
        __align__(16) u16 tmp[8];
#pragma unroll
        for (int s = 0; s < 8; s++) tmp[s] = t[kk + s][ccc];
        *(u32x4*)(vt + ((size_t)bh * 64 + ccc) * 1024 + t0 + kk) = *(u32x4*)tmp;
    }
}

// ===================== QKV GEMM (unchanged, validated) ========================
__global__ __launch_bounds__(256) void k_gemm_qkv(
    const void* __restrict__ X, const u16* __restrict__ WT,
    u16* __restrict__ qb, u16* __restrict__ kb, u16* __restrict__ vb,
    const u32* __restrict__ flag)
{
    const bool isb = (*flag != 0);
    __shared__ __align__(16) u16 As[64][40];
    __shared__ __align__(16) u16 Bs[64][40];
    const int tid = threadIdx.x;
    const int wave = tid >> 6, lane = tid & 63, quad = lane >> 4, l15 = lane & 15;
    const int wr = wave >> 1, wc = wave & 1;
    const int m0 = blockIdx.y * 64, c0 = blockIdx.x * 64;
    f32x4 acc[2][2];
#pragma unroll
    for (int i = 0; i < 2; i++)
#pragma unroll
        for (int j = 0; j < 2; j++) acc[i][j] = (f32x4){0.f, 0.f, 0.f, 0.f};
    const int ar = tid >> 2, akc = (tid & 3) * 8;
    const u16*   a16 = (const u16*)X   + (size_t)(m0 + ar) * 768 + akc;
    const float* a32 = (const float*)X + (size_t)(m0 + ar) * 768 + akc;
    const u16* bptr = WT + (size_t)(c0 + ar) * 768 + akc;
    for (int k0 = 0; k0 < 768; k0 += 32) {
        u32x4 av = isb ? *(const u32x4*)(a16 + k0) : cvt8(a32 + k0);
        u32x4 bv = *(const u32x4*)(bptr + k0);
        __syncthreads();
        *(u32x4*)&As[ar][akc] = av;
        *(u32x4*)&Bs[ar][akc] = bv;
        __syncthreads();
#pragma unroll
        for (int mi = 0; mi < 2; mi++) {
            u32x4 af = *(const u32x4*)&As[wr * 32 + mi * 16 + l15][quad * 8];
#pragma unroll
            for (int ni = 0; ni < 2; ni++) {
                u32x4 bf = *(const u32x4*)&Bs[wc * 32 + ni * 16 + l15][quad * 8];
                acc[mi][ni] = mfma16(af, bf, acc[mi][ni]);
            }
        }
    }
#pragma unroll
    for (int mi = 0; mi < 2; mi++) {
#pragma unroll
        for (int ni = 0; ni < 2; ni++) {
            const int c = c0 + wc * 32 + ni * 16 + l15;
            const int sector = c / 768, hc = c % 768;
            const int h = hc >> 6, d = hc & 63;
            u16* dst = sector == 0 ? qb : (sector == 1 ? kb : vb);
#pragma unroll
            for (int r = 0; r < 4; r++) {
                const int tok = m0 + wr * 32 + mi * 16 + quad * 4 + r;
                const int b = tok >> 10, n = tok & 1023;
                dst[(((size_t)b * 12 + h) * 1024 + n) * 64 + d] = f2bf(acc[mi][ni][r]);
            }
        }
    }
}

// ===================== output GEMM (unchanged, validated; fp32 out) ===========
__global__ __launch_bounds__(256) void k_gemm_out(
    const u16* __restrict__ O, const u16* __restrict__ WoT, const void* __restrict__ bo,
    float* __restrict__ out, const u32* __restrict__ flag)
{
    const bool isb = (*flag != 0);
    __shared__ __align__(16) u16 As[64][40];
    __shared__ __align__(16) u16 Bs[64][40];
    const int tid = threadIdx.x;
    const int wave = tid >> 6, lane = tid & 63, quad = lane >> 4, l15 = lane & 15;
    const int wr = wave >> 1, wc = wave & 1;
    const int m0 = blockIdx.y * 64, c0 = blockIdx.x * 64;
    f32x4 acc[2][2];
#pragma unroll
    for (int i = 0; i < 2; i++)
#pragma unroll
        for (int j = 0; j < 2; j++) acc[i][j] = (f32x4){0.f, 0.f, 0.f, 0.f};
    const int ar = tid >> 2, akc = (tid & 3) * 8;
    const u16* aptr = O   + (size_t)(m0 + ar) * 768 + akc;
    const u16* bptr = WoT + (size_t)(c0 + ar) * 768 + akc;
    for (int k0 = 0; k0 < 768; k0 += 32) {
        u32x4 av = *(const u32x4*)(aptr + k0);
        u32x4 bv = *(const u32x4*)(bptr + k0);
        __syncthreads();
        *(u32x4*)&As[ar][akc] = av;
        *(u32x4*)&Bs[ar][akc] = bv;
        __syncthreads();
#pragma unroll
        for (int mi = 0; mi < 2; mi++) {
            u32x4 af = *(const u32x4*)&As[wr * 32 + mi * 16 + l15][quad * 8];
#pragma unroll
            for (int ni = 0; ni < 2; ni++) {
                u32x4 bf = *(const u32x4*)&Bs[wc * 32 + ni * 16 + l15][quad * 8];
                acc[mi][ni] = mfma16(af, bf, acc[mi][ni]);
            }
        }
    }
#pragma unroll
    for (int mi = 0; mi < 2; mi++) {
#pragma unroll
        for (int ni = 0; ni < 2; ni++) {
            const int c = c0 + wc * 32 + ni * 16 + l15;
            const float biasv = isb ? bf2f(((const u16*)bo)[c]) : ((const float*)bo)[c];
#pragma unroll
            for (int r = 0; r < 4; r++) {
                const int tok = m0 + wr * 32 + mi * 16 + quad * 4 + r;
                out[(size_t)tok * 768 + c] = acc[mi][ni][r] + biasv;
            }
        }
    }
}

// =====================================================================
// k_attn v3: spill unnormalized probs e=exp(premixed) to global E in the
// postmix-B-frag layout [n][h] (h-pitch 16, bf16). Pass 2 reloads E with
// coalesced b128 and feeds the postmix MFMA directly — no QK^T recompute,
// no score write, no premix, no exp in pass 2. 1/l folds into the postmix
// A-fragment per slice (one i per 16-wide slice): A'[g][h]=mpost[h,g]*invl[h][i],
// hoisted out of the j-loop (slice->wave map is jt-independent).
// LDS: SP (pass 1) and Abuf (pass 2) unioned = 36,864 B + invlT 1 KB.
// =====================================================================
__global__ __launch_bounds__(768) void k_attn(
    const u16* __restrict__ qb, const u16* __restrict__ kb, const u16* __restrict__ vt,
    const void* __restrict__ mixpre, const void* __restrict__ mixpost,
    u16* __restrict__ ob, u16* __restrict__ E, const u32* __restrict__ flag)
{
    __shared__ __align__(16) u16 LDSU[18432];      // 36,864 B union: SP (p1) / Abuf (p2)
    __shared__ float invlT[256];                   // [i][h] 16x16 f32
    u16* SP   = LDSU;
    u32* SP32 = (u32*)LDSU;
    u16* Abuf = LDSU;
    float* red = (float*)LDSU;                     // 4 KB reduction scratch (between passes)

    const bool isb = (*flag != 0);
    const int tid = threadIdx.x;
    const int w = tid >> 6, lane = tid & 63, quad = lane >> 4, l15 = lane & 15;
    const int b = blockIdx.y, qx = blockIdx.x, i0 = qx * 16;
    u16* Ewg = E + ((size_t)(b * 64 + qx)) * (16384 * 16);

    // zero SP pad head-cols 12..15 (u32 cols 6,7) for the premix B-frag
    for (int n = tid; n < 1024; n += 768) { SP32[n * 9 + 6] = 0; SP32[n * 9 + 7] = 0; }

    // mixpre as MFMA A-frag (validated round 4); mixpost held as f32 regs
    u32x4 apre = (u32x4){0, 0, 0, 0};
    float mpostF[8];
#pragma unroll
    for (int j = 0; j < 8; j++) {
        const int h = quad * 8 + j;
        mpostF[j] = 0.f;
        if (quad < 2 && l15 < 12 && h < 12) {
            mpostF[j] = isb ? bf2f(((const u16*)mixpost)[h * 12 + l15])
                            : ((const float*)mixpost)[h * 12 + l15];
            u16 v1 = isb ? ((const u16*)mixpre)[h * 12 + l15]
                         : f2bf(((const float*)mixpre)[h * 12 + l15]);
            apre[j >> 1] |= ((u32)v1) << ((j & 1) * 16);
        }
    }

    const u16* qh = qb + (((size_t)b * 12 + w) * 1024 + i0) * 64;
    u32x4 aq[2];
#pragma unroll
    for (int kc = 0; kc < 2; kc++)
        aq[kc] = *(const u32x4*)(qh + l15 * 64 + kc * 32 + quad * 8);
    const u16* kh = kb + ((size_t)b * 12 + w) * 1024 * 64;
    const u16* vh = vt + ((size_t)b * 12 + w) * 64 * 1024;

    // ---------------- pass 1: QK^T -> premix -> exp -> E + row sums ----------
    f32x4 part[6];
#pragma unroll
    for (int t = 0; t < 6; t++) part[t] = (f32x4){0.f, 0.f, 0.f, 0.f};

    for (int jt = 0; jt < 16; jt++) {
        const int j0 = jt * 64;
        f32x4 sc[4];
#pragma unroll
        for (int nt = 0; nt < 4; nt++) {
            f32x4 a = (f32x4){0.f, 0.f, 0.f, 0.f};
#pragma unroll
            for (int kc = 0; kc < 2; kc++) {
                u32x4 bfr = *(const u32x4*)(kh + (size_t)(j0 + nt * 16 + l15) * 64 + kc * 32 + quad * 8);
                a = mfma16(aq[kc], bfr, a);
            }
            sc[nt] = a;
        }
        __syncthreads();   // prior jt premix reads done
#pragma unroll
        for (int nt = 0; nt < 4; nt++)
#pragma unroll
            for (int r = 0; r < 4; r++)
                SP[((quad * 4 + r) * 64 + nt * 16 + l15) * 18 + w] = f2bf(sc[nt][r] * 0.125f);
        __syncthreads();   // scores visible
#pragma unroll
        for (int t = 0; t < 6; t++) {
            const int s = w + 12 * t;
            if (s < 64) {
                u32x4 bfr = (u32x4){0, 0, 0, 0};
                if (quad < 2) {
                    const u32* p = SP32 + (s * 16 + l15) * 9 + quad * 4;
                    bfr[0] = p[0]; bfr[1] = p[1]; bfr[2] = p[2]; bfr[3] = p[3];
                }
                f32x4 d = mfma16(apre, bfr, (f32x4){0.f, 0.f, 0.f, 0.f});
                u16* ep = Ewg + ((size_t)jt * 1024 + s * 16 + l15) * 16;
#pragma unroll
                for (int r = 0; r < 4; r++) {
                    const float e = __expf(d[r]);
                    part[t][r] += e;
                    const int g = quad * 4 + r;
                    if (g < 12) ep[g] = f2bf(e);
                }
            }
        }
    }
    __syncthreads();       // last premix SP reads done; SP region -> red scratch
    // cross-lane j reduction into red[(i*16+h)*4 + jblk]
#pragma unroll
    for (int t = 0; t < 6; t++) {
        const int s = w + 12 * t;
        if (s < 64) {
#pragma unroll
            for (int r = 0; r < 4; r++) {
                float v = part[t][r];
#pragma unroll
                for (int off = 1; off < 16; off <<= 1) v += __shfl_xor(v, off);
                if (l15 == 0) red[(((s >> 2) * 16) + quad * 4 + r) * 4 + (s & 3)] = v;
            }
        }
    }
    __syncthreads();
    if (tid < 256) {
        const int h = tid & 15;
        float v = 0.f;
        if (h < 12) {
            const float* q = &red[tid * 4];
            v = 1.f / (q[0] + q[1] + q[2] + q[3]);
        }
        invlT[tid] = v;
    }
    __syncthreads();       // invlT ready; red dead; LDSU becomes Abuf

    // hoisted postmix A-frags: A'[g][h] = mpost[h,g] * invl[h][i(s)]
    u32x4 Afr[6];
#pragma unroll
    for (int t = 0; t < 6; t++) {
        const int s = w + 12 * t;
        Afr[t] = (u32x4){0, 0, 0, 0};
        if (s < 64 && quad < 2) {
            const int i = s >> 2;
#pragma unroll
            for (int j = 0; j < 8; j++) {
                const u16 v = f2bf(mpostF[j] * invlT[i * 16 + quad * 8 + j]);
                Afr[t][j >> 1] |= ((u32)v) << ((j & 1) * 16);
            }
        }
    }

    // ---------------- pass 2: reload E -> postmix -> PV ----------------------
    f32x4 oacc[4];
#pragma unroll
    for (int nt = 0; nt < 4; nt++) oacc[nt] = (f32x4){0.f, 0.f, 0.f, 0.f};

    for (int jt = 0; jt < 16; jt++) {
        const int j0 = jt * 64;
#pragma unroll
        for (int t = 0; t < 6; t++) {
            const int s = w + 12 * t;
            if (s < 64) {
                const int i = s >> 2, jq = s & 3;
                u32x4 ef = (u32x4){0, 0, 0, 0};
                if (quad < 2)
                    ef = *(const u32x4*)(Ewg + ((size_t)jt * 1024 + s * 16 + l15) * 16 + quad * 8);
                f32x4 am = mfma16(Afr[t], ef, (f32x4){0.f, 0.f, 0.f, 0.f});
#pragma unroll
                for (int r = 0; r < 4; r++) {
                    const int g2 = quad * 4 + r;
                    if (g2 < 12)
                        Abuf[g2 * 1160 + i * 72 + jq * 16 + l15] = f2bf(am[r]);
                }
            }
        }
        __syncthreads();   // amix visible
#pragma unroll
        for (int kc = 0; kc < 2; kc++) {
            u32x4 af = *(const u32x4*)&Abuf[w * 1160 + l15 * 72 + kc * 32 + quad * 8];
#pragma unroll
            for (int nt = 0; nt < 4; nt++) {
                u32x4 vf = *(const u32x4*)(vh + (size_t)(nt * 16 + l15) * 1024 + j0 + kc * 32 + quad * 8);
                oacc[nt] = mfma16(af, vf, oacc[nt]);
            }
        }
        __syncthreads();   // Abuf free for next jt
    }
#pragma unroll
    for (int nt = 0; nt < 4; nt++)
#pragma unroll
        for (int r = 0; r < 4; r++)
            ob[((size_t)b * 1024 + i0 + quad * 4 + r) * 768 + w * 64 + nt * 16 + l15] =
                f2bf(oacc[nt][r]);
}

// =====================================================================
// k_attn_fb: round-4 kernel, kept verbatim as fallback if ws_size cannot
// hold the 268 MB E spill buffer.
// =====================================================================
__global__ __launch_bounds__(768) void k_attn_fb(
    const u16* __restrict__ qb, const u16* __restrict__ kb, const u16* __restrict__ vt,
    const void* __restrict__ mixpre, const void* __restrict__ mixpost,
    u16* __restrict__ ob, const u32* __restrict__ flag)
{
    __shared__ __align__(16) u16 SP[1024 * 18];
    __shared__ __align__(16) u16 Abuf[12 * 1160];
    u32* SP32 = (u32*)SP;
    float* red = (float*)Abuf;

    const bool isb = (*flag != 0);
    const int tid = threadIdx.x;
    const int w = tid >> 6, lane = tid & 63, quad = lane >> 4, l15 = lane & 15;
    const int b = blockIdx.y, i0 = blockIdx.x * 16;

    for (int n = tid; n < 1024; n += 768) { SP32[n * 9 + 6] = 0; SP32[n * 9 + 7] = 0; }

    u32x4 apre = (u32x4){0, 0, 0, 0}, apost = (u32x4){0, 0, 0, 0};
    if (quad < 2 && l15 < 12) {
#pragma unroll
        for (int j = 0; j < 8; j++) {
            const int h = quad * 8 + j;
            u16 v1 = 0, v2 = 0;
            if (h < 12) {
                v1 = isb ? ((const u16*)mixpre)[h * 12 + l15]  : f2bf(((const float*)mixpre)[h * 12 + l15]);
                v2 = isb ? ((const u16*)mixpost)[h * 12 + l15] : f2bf(((const float*)mixpost)[h * 12 + l15]);
            }
            apre[j >> 1]  |= ((u32)v1) << ((j & 1) * 16);
            apost[j >> 1] |= ((u32)v2) << ((j & 1) * 16);
        }
    }

    const u16* qh = qb + (((size_t)b * 12 + w) * 1024 + i0) * 64;
    u32x4 aq[2];
#pragma unroll
    for (int kc = 0; kc < 2; kc++)
        aq[kc] = *(const u32x4*)(qh + l15 * 64 + kc * 32 + quad * 8);
    const u16* kh = kb + ((size_t)b * 12 + w) * 1024 * 64;
    const u16* vh = vt + ((size_t)b * 12 + w) * 64 * 1024;

    f32x4 part[6];
#pragma unroll
    for (int t = 0; t < 6; t++) part[t] = (f32x4){0.f, 0.f, 0.f, 0.f};

    for (int jt = 0; jt < 16; jt++) {
        const int j0 = jt * 64;
        f32x4 sc[4];
#pragma unroll
        for (int nt = 0; nt < 4; nt++) {
            f32x4 a = (f32x4){0.f, 0.f, 0.f, 0.f};
#pragma unroll
            for (int kc = 0; kc < 2; kc++) {
                u32x4 bfr = *(const u32x4*)(kh + (size_t)(j0 + nt * 16 + l15) * 64 + kc * 32 + quad * 8);
                a = mfma16(aq[kc], bfr, a);
            }
            sc[nt] = a;
        }
        __syncthreads();
#pragma unroll
        for (int nt = 0; nt < 4; nt++)
#pragma unroll
            for (int r = 0; r < 4; r++)
                SP[((quad * 4 + r) * 64 + nt * 16 + l15) * 18 + w] = f2bf(sc[nt][r] * 0.125f);
        __syncthreads();
#pragma unroll
        for (int t = 0; t < 6; t++) {
            const int s = w + 12 * t;
            if (s < 64) {
                u32x4 bfr = (u32x4){0, 0, 0, 0};
                if (quad < 2) {
                    const u32* p = SP32 + (s * 16 + l15) * 9 + quad * 4;
                    bfr[0] = p[0]; bfr[1] = p[1]; bfr[2] = p[2]; bfr[3] = p[3];
                }
                f32x4 d = mfma16(apre, bfr, (f32x4){0.f, 0.f, 0.f, 0.f});
#pragma unroll
                for (int r = 0; r < 4; r++) part[t][r] += __expf(d[r]);
            }
        }
    }
    __syncthreads();
#pragma unroll
    for (int t = 0; t < 6; t++) {
        const int s = w + 12 * t;
        if (s < 64) {
#pragma unroll
            for (int r = 0; r < 4; r++) {
                float v = part[t][r];
#pragma unroll
                for (int off = 1; off < 16; off <<= 1) v += __shfl_xor(v, off);
                if (l15 == 0) red[(((s >> 2) * 16) + quad * 4 + r) * 4 + (s & 3)] = v;
            }
        }
    }
    __syncthreads();
    f32x4 invl[6];
#pragma unroll
    for (int t = 0; t < 6; t++) {
        const int s = w + 12 * t;
        invl[t] = (f32x4){0.f, 0.f, 0.f, 0.f};
        if (s < 64) {
#pragma unroll
            for (int r = 0; r < 4; r++) {
                const f32x4 v4 = *(const f32x4*)&red[(((s >> 2) * 16) + quad * 4 + r) * 4];
                invl[t][r] = 1.f / (v4[0] + v4[1] + v4[2] + v4[3]);
            }
        }
    }

    f32x4 oacc[4];
#pragma unroll
    for (int nt = 0; nt < 4; nt++) oacc[nt] = (f32x4){0.f, 0.f, 0.f, 0.f};

    for (int jt = 0; jt < 16; jt++) {
        const int j0 = jt * 64;
        f32x4 sc[4];
#pragma unroll
        for (int nt = 0; nt < 4; nt++) {
            f32x4 a = (f32x4){0.f, 0.f, 0.f, 0.f};
#pragma unroll
            for (int kc = 0; kc < 2; kc++) {
                u32x4 bfr = *(const u32x4*)(kh + (size_t)(j0 + nt * 16 + l15) * 64 + kc * 32 + quad * 8);
                a = mfma16(aq[kc], bfr, a);
            }
            sc[nt] = a;
        }
        __syncthreads();
#pragma unroll
        for (int nt = 0; nt < 4; nt++)
#pragma unroll
            for (int r = 0; r < 4; r++)
                SP[((quad * 4 + r) * 64 + nt * 16 + l15) * 18 + w] = f2bf(sc[nt][r] * 0.125f);
        __syncthreads();
#pragma unroll
        for (int t = 0; t < 6; t++) {
            const int s = w + 12 * t;
            if (s < 64) {
                const int row = s * 16 + l15, i = s >> 2, jq = s & 3;
                u32x4 bfr = (u32x4){0, 0, 0, 0};
                if (quad < 2) {
                    const u32* p = SP32 + row * 9 + quad * 4;
                    bfr[0] = p[0]; bfr[1] = p[1]; bfr[2] = p[2]; bfr[3] = p[3];
                }
                f32x4 d = mfma16(apre, bfr, (f32x4){0.f, 0.f, 0.f, 0.f});
                u16 p0 = f2bf(__expf(d[0]) * invl[t][0]);
                u16 p1 = f2bf(__expf(d[1]) * invl[t][1]);
                u16 p2 = f2bf(__expf(d[2]) * invl[t][2]);
                u16 p3 = f2bf(__expf(d[3]) * invl[t][3]);
                SP32[row * 9 + quad * 2]     = (u32)p0 | ((u32)p1 << 16);
                SP32[row * 9 + quad * 2 + 1] = (u32)p2 | ((u32)p3 << 16);
                __asm__ volatile("s_waitcnt lgkmcnt(0)" ::: "memory");
                u32x4 bfp = (u32x4){0, 0, 0, 0};
                if (quad < 2) {
                    const u32* p = SP32 + row * 9 + quad * 4;
                    bfp[0] = p[0]; bfp[1] = p[1]; bfp[2] = p[2]; bfp[3] = p[3];
                }
                f32x4 am = mfma16(apost, bfp, (f32x4){0.f, 0.f, 0.f, 0.f});
#pragma unroll
                for (int r = 0; r < 4; r++) {
                    const int g2 = quad * 4 + r;
                    if (g2 < 12)
                        Abuf[g2 * 1160 + i * 72 + jq * 16 + l15] = f2bf(am[r]);
                }
            }
        }
        __syncthreads();
#pragma unroll
        for (int kc = 0; kc < 2; kc++) {
            u32x4 af = *(const u32x4*)&Abuf[w * 1160 + l15 * 72 + kc * 32 + quad * 8];
#pragma unroll
            for (int nt = 0; nt < 4; nt++) {
                u32x4 vf = *(const u32x4*)(vh + (size_t)(nt * 16 + l15) * 1024 + j0 + kc * 32 + quad * 8);
                oacc[nt] = mfma16(af, vf, oacc[nt]);
            }
        }
    }
#pragma unroll
    for (int nt = 0; nt < 4; nt++)
#pragma unroll
        for (int r = 0; r < 4; r++)
            ob[((size_t)b * 1024 + i0 + quad * 4 + r) * 768 + w * 64 + nt * 16 + l15] =
                f2bf(oacc[nt][r]);
}

// =====================================================================
extern "C" void kernel_launch(void* const* d_in, const int* in_sizes, int n_in,
                              void* d_out, int out_size, void* d_ws, size_t ws_size,
                              hipStream_t stream)
{
    float* out = (float*)d_out;

    u32* flag = (u32*)d_ws;
    u16* base = (u16*)d_ws + 128;
    u16* WT   = base;                        // 1,769,472 u16
    u16* WoT  = WT  + 2304 * 768;            // 589,824
    u16* qb   = WoT + 768 * 768;             // 6,291,456
    u16* kb   = qb  + 6291456;
    u16* vtb  = kb  + 6291456;
    u16* obuf = vtb + 6291456;               // aliases vb (v dead after transpose)
    u16* vb   = obuf;
    u16* E    = obuf + 6291456;              // 134,217,728 u16 = 268 MB spill

    const size_t need = 256 + 2ull * (2304 * 768 + 768 * 768 + 4ull * 6291456 + 134217728ull);
    const bool use_spill = (ws_size >= need);

    k_detect     <<<dim3(1), 64,  0, stream>>>((const u16*)d_in[0], flag);
    k_transpose_w<<<dim3(12, 24, 3), 256, 0, stream>>>(d_in[1], d_in[2], d_in[5], WT, WoT, flag);
    k_gemm_qkv   <<<dim3(36, 128),   256, 0, stream>>>(d_in[0], WT, qb, kb, vb, flag);
    k_transpose_v<<<dim3(16, 1, 96), 256, 0, stream>>>(vb, vtb);
    if (use_spill)
        k_attn   <<<dim3(64, 8),     768, 0, stream>>>(qb, kb, vtb, d_in[3], d_in[4], obuf, E, flag);
    else
        k_attn_fb<<<dim3(64, 8),     768, 0, stream>>>(qb, kb, vtb, d_in[3], d_in[4], obuf, flag);
    k_gemm_out   <<<dim3(12, 128),   256, 0, stream>>>(obuf, WoT, d_in[6], out, flag);
}

// Round 6
// 520.057 us; speedup vs baseline: 1.1128x; 1.1128x over previous
//
#include <hip/hip_runtime.h>
#include <cstdint>
#include <cstddef>

typedef unsigned short u16;
typedef unsigned int u32;

typedef __bf16 bf16x8 __attribute__((ext_vector_type(8)));
typedef float f32x4 __attribute__((ext_vector_type(4)));
typedef u32 u32x4 __attribute__((ext_vector_type(4)));
typedef u32 u32x2 __attribute__((ext_vector_type(2)));

__device__ inline float bf2f(u16 u) {
    union { u32 i; float f; } c; c.i = ((u32)u) << 16; return c.f;
}
__device__ inline u16 f2bf(float f) {
    union { float f; u32 i; } c; c.f = f;
    u32 u = c.i;
    return (u16)((u + 0x7fffu + ((u >> 16) & 1u)) >> 16);  // RNE
}
__device__ inline f32x4 mfma16(u32x4 a, u32x4 b, f32x4 c) {
    return __builtin_amdgcn_mfma_f32_16x16x32_bf16(
        __builtin_bit_cast(bf16x8, a), __builtin_bit_cast(bf16x8, b), c, 0, 0, 0);
}
__device__ inline u32x4 cvt8(const float* p) {
    f32x4 a = *(const f32x4*)p, b = *(const f32x4*)(p + 4);
    u32x4 v;
    v[0] = (u32)f2bf(a[0]) | ((u32)f2bf(a[1]) << 16);
    v[1] = (u32)f2bf(a[2]) | ((u32)f2bf(a[3]) << 16);
    v[2] = (u32)f2bf(b[0]) | ((u32)f2bf(b[1]) << 16);
    v[3] = (u32)f2bf(b[2]) | ((u32)f2bf(b[3]) << 16);
    return v;
}

// ===================== dtype detector (round-1 forensics: inputs fp32) ========
__global__ __launch_bounds__(64) void k_detect(const u16* __restrict__ x, u32* __restrict__ flag)
{
    const int lane = threadIdx.x;
    int cnt = 0;
#pragma unroll
    for (int i = 0; i < 4; i++) {
        u32 e = (x[lane * 4 + i] >> 7) & 0xFF;
        cnt += (e >= 115 && e <= 133) ? 1 : 0;
    }
#pragma unroll
    for (int off = 1; off < 64; off <<= 1) cnt += __shfl_xor(cnt, off);
    if (lane == 0) *flag = (cnt >= 192) ? 1u : 0u;
}

// ===================== weight transpose (unchanged, validated) ================
__global__ __launch_bounds__(256) void k_transpose_w(
    const void* __restrict__ Wq, const void* __restrict__ Wkv, const void* __restrict__ Wo,
    u16* __restrict__ WT, u16* __restrict__ WoT, const u32* __restrict__ flag)
{
    const bool isb = (*flag != 0);
    __shared__ __align__(16) u16 t[64][72];
    const int z = blockIdx.z;
    const void* src; u16* dst; int C;
    if (z == 0)      { src = Wq;  dst = WT;             C = 768;  }
    else if (z == 1) { src = Wkv; dst = WT + 768 * 768; C = 1536; }
    else             { src = Wo;  dst = WoT;            C = 768;  }
    const int c0 = blockIdx.y * 64;
    if (c0 >= C) return;
    const int k0 = blockIdx.x * 64;
    const int tid = threadIdx.x;
    const int r = tid >> 3, cc = (tid & 7) * 8;
    if (isb) {
        const u16* s = (const u16*)src;
        for (int rr = r; rr < 64; rr += 32)
            *(u32x4*)&t[rr][cc] = *(const u32x4*)(s + (size_t)(k0 + rr) * C + c0 + cc);
    } else {
        const float* s = (const float*)src;
        for (int rr = r; rr < 64; rr += 32)
            *(u32x4*)&t[rr][cc] = cvt8(s + (size_t)(k0 + rr) * C + c0 + cc);
    }
    __syncthreads();
    const int kk = (tid & 7) * 8;
    for (int ccc = tid >> 3; ccc < 64; ccc += 32) {
        __align__(16) u16 tmp[8];
#pragma unroll
        for (int s = 0; s < 8; s++) tmp[s] = t[kk + s][ccc];
        *(u32x4*)(dst + (size_t)(c0 + ccc) * 768 + k0 + kk) = *(u32x4*)tmp;
    }
}

// ===================== v transpose (unchanged, validated) =====================
__global__ __launch_bounds__(256) void k_transpose_v(
    const u16* __restrict__ v, u16* __restrict__ vt)
{
    __shared__ __align__(16) u16 t[64][72];
    const int bh = blockIdx.z;
    const int t0 = blockIdx.x * 64;
    const int tid = threadIdx.x;
    const int r = tid >> 3, cc = (tid & 7) * 8;
    for (int rr = r; rr < 64; rr += 32)
        *(u32x4*)&t[rr][cc] = *(const u32x4*)(v + ((size_t)bh * 1024 + t0 + rr) * 64 + cc);
    __syncthreads();
    const int kk = (tid & 7) * 8;
    for (int ccc = tid >> 3; ccc < 64; ccc += 32) {
        __align__(16) u16 tmp[8];
#pragma unroll
        for (int s = 0; s < 8; s++) tmp[s] = t[kk + s][ccc];
        *(u32x4*)(vt + ((size_t)bh * 64 + ccc) * 1024 + t0 + kk) = *(u32x4*)tmp;
    }
}

// ===================== QKV GEMM (unchanged, validated) ========================
__global__ __launch_bounds__(256) void k_gemm_qkv(
    const void* __restrict__ X, const u16* __restrict__ WT,
    u16* __restrict__ qb, u16* __restrict__ kb, u16* __restrict__ vb,
    const u32* __restrict__ flag)
{
    const bool isb = (*flag != 0);
    __shared__ __align__(16) u16 As[64][40];
    __shared__ __align__(16) u16 Bs[64][40];
    const int tid = threadIdx.x;
    const int wave = tid >> 6, lane = tid & 63, quad = lane >> 4, l15 = lane & 15;
    const int wr = wave >> 1, wc = wave & 1;
    const int m0 = blockIdx.y * 64, c0 = blockIdx.x * 64;
    f32x4 acc[2][2];
#pragma unroll
    for (int i = 0; i < 2; i++)
#pragma unroll
        for (int j = 0; j < 2; j++) acc[i][j] = (f32x4){0.f, 0.f, 0.f, 0.f};
    const int ar = tid >> 2, akc = (tid & 3) * 8;
    const u16*   a16 = (const u16*)X   + (size_t)(m0 + ar) * 768 + akc;
    const float* a32 = (const float*)X + (size_t)(m0 + ar) * 768 + akc;
    const u16* bptr = WT + (size_t)(c0 + ar) * 768 + akc;
    for (int k0 = 0; k0 < 768; k0 += 32) {
        u32x4 av = isb ? *(const u32x4*)(a16 + k0) : cvt8(a32 + k0);
        u32x4 bv = *(const u32x4*)(bptr + k0);
        __syncthreads();
        *(u32x4*)&As[ar][akc] = av;
        *(u32x4*)&Bs[ar][akc] = bv;
        __syncthreads();
#pragma unroll
        for (int mi = 0; mi < 2; mi++) {
            u32x4 af = *(const u32x4*)&As[wr * 32 + mi * 16 + l15][quad * 8];
#pragma unroll
            for (int ni = 0; ni < 2; ni++) {
                u32x4 bf = *(const u32x4*)&Bs[wc * 32 + ni * 16 + l15][quad * 8];
                acc[mi][ni] = mfma16(af, bf, acc[mi][ni]);
            }
        }
    }
#pragma unroll
    for (int mi = 0; mi < 2; mi++) {
#pragma unroll
        for (int ni = 0; ni < 2; ni++) {
            const int c = c0 + wc * 32 + ni * 16 + l15;
            const int sector = c / 768, hc = c % 768;
            const int h = hc >> 6, d = hc & 63;
            u16* dst = sector == 0 ? qb : (sector == 1 ? kb : vb);
#pragma unroll
            for (int r = 0; r < 4; r++) {
                const int tok = m0 + wr * 32 + mi * 16 + quad * 4 + r;
                const int b = tok >> 10, n = tok & 1023;
                dst[(((size_t)b * 12 + h) * 1024 + n) * 64 + d] = f2bf(acc[mi][ni][r]);
            }
        }
    }
}

// ===================== output GEMM (unchanged, validated; fp32 out) ===========
__global__ __launch_bounds__(256) void k_gemm_out(
    const u16* __restrict__ O, const u16* __restrict__ WoT, const void* __restrict__ bo,
    float* __restrict__ out, const u32* __restrict__ flag)
{
    const bool isb = (*flag != 0);
    __shared__ __align__(16) u16 As[64][40];
    __shared__ __align__(16) u16 Bs[64][40];
    const int tid = threadIdx.x;
    const int wave = tid >> 6, lane = tid & 63, quad = lane >> 4, l15 = lane & 15;
    const int wr = wave >> 1, wc = wave & 1;
    const int m0 = blockIdx.y * 64, c0 = blockIdx.x * 64;
    f32x4 acc[2][2];
#pragma unroll
    for (int i = 0; i < 2; i++)
#pragma unroll
        for (int j = 0; j < 2; j++) acc[i][j] = (f32x4){0.f, 0.f, 0.f, 0.f};
    const int ar = tid >> 2, akc = (tid & 3) * 8;
    const u16* aptr = O   + (size_t)(m0 + ar) * 768 + akc;
    const u16* bptr = WoT + (size_t)(c0 + ar) * 768 + akc;
    for (int k0 = 0; k0 < 768; k0 += 32) {
        u32x4 av = *(const u32x4*)(aptr + k0);
        u32x4 bv = *(const u32x4*)(bptr + k0);
        __syncthreads();
        *(u32x4*)&As[ar][akc] = av;
        *(u32x4*)&Bs[ar][akc] = bv;
        __syncthreads();
#pragma unroll
        for (int mi = 0; mi < 2; mi++) {
            u32x4 af = *(const u32x4*)&As[wr * 32 + mi * 16 + l15][quad * 8];
#pragma unroll
            for (int ni = 0; ni < 2; ni++) {
                u32x4 bf = *(const u32x4*)&Bs[wc * 32 + ni * 16 + l15][quad * 8];
                acc[mi][ni] = mfma16(af, bf, acc[mi][ni]);
            }
        }
    }
#pragma unroll
    for (int mi = 0; mi < 2; mi++) {
#pragma unroll
        for (int ni = 0; ni < 2; ni++) {
            const int c = c0 + wc * 32 + ni * 16 + l15;
            const float biasv = isb ? bf2f(((const u16*)bo)[c]) : ((const float*)bo)[c];
#pragma unroll
            for (int r = 0; r < 4; r++) {
                const int tok = m0 + wr * 32 + mi * 16 + quad * 4 + r;
                out[(size_t)tok * 768 + c] = acc[mi][ni][r] + biasv;
            }
        }
    }
}

// =====================================================================
// k_attn v4: E-spill talking-heads attention, pitch-12 E, runtime tiling.
// Each WG owns one E slot (16384 rows x 12 h, bf16, 24B rows) reused
// across `tiles` sequential q-tiles (qx = blockIdx.x + tt*gridDim.x).
// Pass 1: QK^T -> SP[n][h] -> premix MFMA -> exp -> packed E store + sums.
// Pass 2: E reload (2x dwordx2) -> (mpost*1/l)-folded MFMA -> Abuf -> PV.
// quad1's k-lanes h12..15 read past the 24B row (next row h0..3): finite
// garbage multiplied by Afr zeros. E zone padded +64B for the last row.
// =====================================================================
__global__ __launch_bounds__(768) void k_attn(
    const u16* __restrict__ qb, const u16* __restrict__ kb, const u16* __restrict__ vt,
    const void* __restrict__ mixpre, const void* __restrict__ mixpost,
    u16* __restrict__ ob, u16* __restrict__ E, const u32* __restrict__ flag, int tiles)
{
    __shared__ __align__(16) u16 LDSU[18432];      // 36,864 B union: SP (p1) / Abuf (p2)
    __shared__ float invlT[256];                   // [i][h] 16x16 f32
    u16* SP   = LDSU;
    u32* SP32 = (u32*)LDSU;
    u16* Abuf = LDSU;
    float* red = (float*)LDSU;

    const bool isb = (*flag != 0);
    const int tid = threadIdx.x;
    const int w = tid >> 6, lane = tid & 63, quad = lane >> 4, l15 = lane & 15;
    const int b = blockIdx.y;
    u16* Ewg = E + (size_t)(b * gridDim.x + blockIdx.x) * (16384 * 12);

    // mixpre as MFMA A-frag; mixpost as f32 regs (folded with 1/l later)
    u32x4 apre = (u32x4){0, 0, 0, 0};
    float mpostF[8];
#pragma unroll
    for (int j = 0; j < 8; j++) {
        const int h = quad * 8 + j;
        mpostF[j] = 0.f;
        if (quad < 2 && l15 < 12 && h < 12) {
            mpostF[j] = isb ? bf2f(((const u16*)mixpost)[h * 12 + l15])
                            : ((const float*)mixpost)[h * 12 + l15];
            u16 v1 = isb ? ((const u16*)mixpre)[h * 12 + l15]
                         : f2bf(((const float*)mixpre)[h * 12 + l15]);
            apre[j >> 1] |= ((u32)v1) << ((j & 1) * 16);
        }
    }

    const u16* kh = kb + ((size_t)b * 12 + w) * 1024 * 64;
    const u16* vh = vt + ((size_t)b * 12 + w) * 64 * 1024;

    for (int tt = 0; tt < tiles; tt++) {
        const int qx = blockIdx.x + tt * gridDim.x;
        const int i0 = qx * 16;

        // (re-)zero SP pad head-cols 12..15 (clobbered by Abuf on prior tile)
        for (int n = tid; n < 1024; n += 768) { SP32[n * 9 + 6] = 0; SP32[n * 9 + 7] = 0; }

        const u16* qh = qb + (((size_t)b * 12 + w) * 1024 + i0) * 64;
        u32x4 aq[2];
#pragma unroll
        for (int kc = 0; kc < 2; kc++)
            aq[kc] = *(const u32x4*)(qh + l15 * 64 + kc * 32 + quad * 8);

        // ---------------- pass 1: QK^T -> premix -> exp -> E + row sums ------
        f32x4 part[6];
#pragma unroll
        for (int t = 0; t < 6; t++) part[t] = (f32x4){0.f, 0.f, 0.f, 0.f};

        for (int jt = 0; jt < 16; jt++) {
            const int j0 = jt * 64;
            f32x4 sc[4];
#pragma unroll
            for (int nt = 0; nt < 4; nt++) {
                f32x4 a = (f32x4){0.f, 0.f, 0.f, 0.f};
#pragma unroll
                for (int kc = 0; kc < 2; kc++) {
                    u32x4 bfr = *(const u32x4*)(kh + (size_t)(j0 + nt * 16 + l15) * 64 + kc * 32 + quad * 8);
                    a = mfma16(aq[kc], bfr, a);
                }
                sc[nt] = a;
            }
            __syncthreads();   // prior jt premix reads done (and tile-start pads visible path)
#pragma unroll
            for (int nt = 0; nt < 4; nt++)
#pragma unroll
                for (int r = 0; r < 4; r++)
                    SP[((quad * 4 + r) * 64 + nt * 16 + l15) * 18 + w] = f2bf(sc[nt][r] * 0.125f);
            __syncthreads();   // scores visible
#pragma unroll
            for (int t = 0; t < 6; t++) {
                const int s = w + 12 * t;
                if (s < 64) {
                    const int row = s * 16 + l15;
                    u32x4 bfr = (u32x4){0, 0, 0, 0};
                    if (quad < 2) {
                        const u32* p = SP32 + row * 9 + quad * 4;
                        bfr[0] = p[0]; bfr[1] = p[1]; bfr[2] = p[2]; bfr[3] = p[3];
                    }
                    f32x4 d = mfma16(apre, bfr, (f32x4){0.f, 0.f, 0.f, 0.f});
                    const float e0 = __expf(d[0]), e1 = __expf(d[1]);
                    const float e2 = __expf(d[2]), e3 = __expf(d[3]);
                    part[t][0] += e0; part[t][1] += e1;
                    part[t][2] += e2; part[t][3] += e3;
                    if (quad < 3) {   // g = quad*4+r, only g<12 stored
                        u32x2 pk;
                        pk[0] = (u32)f2bf(e0) | ((u32)f2bf(e1) << 16);
                        pk[1] = (u32)f2bf(e2) | ((u32)f2bf(e3) << 16);
                        *(u32x2*)(Ewg + ((size_t)jt * 1024 + row) * 12 + quad * 4) = pk;
                    }
                }
            }
        }
        __syncthreads();       // last premix SP reads done; SP region -> red scratch
#pragma unroll
        for (int t = 0; t < 6; t++) {
            const int s = w + 12 * t;
            if (s < 64) {
#pragma unroll
                for (int r = 0; r < 4; r++) {
                    float v = part[t][r];
#pragma unroll
                    for (int off = 1; off < 16; off <<= 1) v += __shfl_xor(v, off);
                    if (l15 == 0) red[(((s >> 2) * 16) + quad * 4 + r) * 4 + (s & 3)] = v;
                }
            }
        }
        __syncthreads();
        if (tid < 256) {
            const int h = tid & 15;
            float v = 0.f;
            if (h < 12) {
                const float* q = &red[tid * 4];
                v = 1.f / (q[0] + q[1] + q[2] + q[3]);
            }
            invlT[tid] = v;
        }
        __syncthreads();       // invlT ready; red dead; LDSU becomes Abuf

        // hoisted postmix A-frags: A'[g][h] = mpost[h,g] * invl[h][i(s)]
        u32x4 Afr[6];
#pragma unroll
        for (int t = 0; t < 6; t++) {
            const int s = w + 12 * t;
            Afr[t] = (u32x4){0, 0, 0, 0};
            if (s < 64 && quad < 2) {
                const int i = s >> 2;
#pragma unroll
                for (int j = 0; j < 8; j++) {
                    const u16 v = f2bf(mpostF[j] * invlT[i * 16 + quad * 8 + j]);
                    Afr[t][j >> 1] |= ((u32)v) << ((j & 1) * 16);
                }
            }
        }

        // ---------------- pass 2: reload E -> postmix -> PV ------------------
        f32x4 oacc[4];
#pragma unroll
        for (int nt = 0; nt < 4; nt++) oacc[nt] = (f32x4){0.f, 0.f, 0.f, 0.f};

        for (int jt = 0; jt < 16; jt++) {
            const int j0 = jt * 64;
#pragma unroll
            for (int t = 0; t < 6; t++) {
                const int s = w + 12 * t;
                if (s < 64) {
                    const int row = s * 16 + l15, i = s >> 2, jq = s & 3;
                    u32x4 ef = (u32x4){0, 0, 0, 0};
                    if (quad < 2) {
                        const u16* ep = Ewg + ((size_t)jt * 1024 + row) * 12 + quad * 8;
                        u32x2 lo = *(const u32x2*)ep;
                        u32x2 hi = *(const u32x2*)(ep + 4);  // quad1 upper 8B: next-row garbage * Afr zeros
                        ef[0] = lo[0]; ef[1] = lo[1]; ef[2] = hi[0]; ef[3] = hi[1];
                    }
                    f32x4 am = mfma16(Afr[t], ef, (f32x4){0.f, 0.f, 0.f, 0.f});
#pragma unroll
                    for (int r = 0; r < 4; r++) {
                        const int g2 = quad * 4 + r;
                        if (g2 < 12)
                            Abuf[g2 * 1160 + i * 72 + jq * 16 + l15] = f2bf(am[r]);
                    }
                }
            }
            __syncthreads();   // amix visible
#pragma unroll
            for (int kc = 0; kc < 2; kc++) {
                u32x4 af = *(const u32x4*)&Abuf[w * 1160 + l15 * 72 + kc * 32 + quad * 8];
#pragma unroll
                for (int nt = 0; nt < 4; nt++) {
                    u32x4 vf = *(const u32x4*)(vh + (size_t)(nt * 16 + l15) * 1024 + j0 + kc * 32 + quad * 8);
                    oacc[nt] = mfma16(af, vf, oacc[nt]);
                }
            }
            __syncthreads();   // Abuf free for next jt
        }
#pragma unroll
        for (int nt = 0; nt < 4; nt++)
#pragma unroll
            for (int r = 0; r < 4; r++)
                ob[((size_t)b * 1024 + i0 + quad * 4 + r) * 768 + w * 64 + nt * 16 + l15] =
                    f2bf(oacc[nt][r]);
    }
}

// =====================================================================
// k_attn_fb: round-4 kernel (399 us), fallback for small ws_size.
// =====================================================================
__global__ __launch_bounds__(768) void k_attn_fb(
    const u16* __restrict__ qb, const u16* __restrict__ kb, const u16* __restrict__ vt,
    const void* __restrict__ mixpre, const void* __restrict__ mixpost,
    u16* __restrict__ ob, const u32* __restrict__ flag)
{
    __shared__ __align__(16) u16 SP[1024 * 18];
    __shared__ __align__(16) u16 Abuf[12 * 1160];
    u32* SP32 = (u32*)SP;
    float* red = (float*)Abuf;

    const bool isb = (*flag != 0);
    const int tid = threadIdx.x;
    const int w = tid >> 6, lane = tid & 63, quad = lane >> 4, l15 = lane & 15;
    const int b = blockIdx.y, i0 = blockIdx.x * 16;

    for (int n = tid; n < 1024; n += 768) { SP32[n * 9 + 6] = 0; SP32[n * 9 + 7] = 0; }

    u32x4 apre = (u32x4){0, 0, 0, 0}, apost = (u32x4){0, 0, 0, 0};
    if (quad < 2 && l15 < 12) {
#pragma unroll
        for (int j = 0; j < 8; j++) {
            const int h = quad * 8 + j;
            u16 v1 = 0, v2 = 0;
            if (h < 12) {
                v1 = isb ? ((const u16*)mixpre)[h * 12 + l15]  : f2bf(((const float*)mixpre)[h * 12 + l15]);
                v2 = isb ? ((const u16*)mixpost)[h * 12 + l15] : f2bf(((const float*)mixpost)[h * 12 + l15]);
            }
            apre[j >> 1]  |= ((u32)v1) << ((j & 1) * 16);
            apost[j >> 1] |= ((u32)v2) << ((j & 1) * 16);
        }
    }

    const u16* qh = qb + (((size_t)b * 12 + w) * 1024 + i0) * 64;
    u32x4 aq[2];
#pragma unroll
    for (int kc = 0; kc < 2; kc++)
        aq[kc] = *(const u32x4*)(qh + l15 * 64 + kc * 32 + quad * 8);
    const u16* kh = kb + ((size_t)b * 12 + w) * 1024 * 64;
    const u16* vh = vt + ((size_t)b * 12 + w) * 64 * 1024;

    f32x4 part[6];
#pragma unroll
    for (int t = 0; t < 6; t++) part[t] = (f32x4){0.f, 0.f, 0.f, 0.f};

    for (int jt = 0; jt < 16; jt++) {
        const int j0 = jt * 64;
        f32x4 sc[4];
#pragma unroll
        for (int nt = 0; nt < 4; nt++) {
            f32x4 a = (f32x4){0.f, 0.f, 0.f, 0.f};
#pragma unroll
            for (int kc = 0; kc < 2; kc++) {
                u32x4 bfr = *(const u32x4*)(kh + (size_t)(j0 + nt * 16 + l15) * 64 + kc * 32 + quad * 8);
                a = mfma16(aq[kc], bfr, a);
            }
            sc[nt] = a;
        }
        __syncthreads();
#pragma unroll
        for (int nt = 0; nt < 4; nt++)
#pragma unroll
            for (int r = 0; r < 4; r++)
                SP[((quad * 4 + r) * 64 + nt * 16 + l15) * 18 + w] = f2bf(sc[nt][r] * 0.125f);
        __syncthreads();
#pragma unroll
        for (int t = 0; t < 6; t++) {
            const int s = w + 12 * t;
            if (s < 64) {
                u32x4 bfr = (u32x4){0, 0, 0, 0};
                if (quad < 2) {
                    const u32* p = SP32 + (s * 16 + l15) * 9 + quad * 4;
                    bfr[0] = p[0]; bfr[1] = p[1]; bfr[2] = p[2]; bfr[3] = p[3];
                }
                f32x4 d = mfma16(apre, bfr, (f32x4){0.f, 0.f, 0.f, 0.f});
#pragma unroll
                for (int r = 0; r < 4; r++) part[t][r] += __expf(d[r]);
            }
        }
    }
    __syncthreads();
#pragma unroll
    for (int t = 0; t < 6; t++) {
        const int s = w + 12 * t;
        if (s < 64) {
#pragma unroll
            for (int r = 0; r < 4; r++) {
                float v = part[t][r];
#pragma unroll
                for (int off = 1; off < 16; off <<= 1) v += __shfl_xor(v, off);
                if (l15 == 0) red[(((s >> 2) * 16) + quad * 4 + r) * 4 + (s & 3)] = v;
            }
        }
    }
    __syncthreads();
    f32x4 invl[6];
#pragma unroll
    for (int t = 0; t < 6; t++) {
        const int s = w + 12 * t;
        invl[t] = (f32x4){0.f, 0.f, 0.f, 0.f};
        if (s < 64) {
#pragma unroll
            for (int r = 0; r < 4; r++) {
                const f32x4 v4 = *(const f32x4*)&red[(((s >> 2) * 16) + quad * 4 + r) * 4];
                invl[t][r] = 1.f / (v4[0] + v4[1] + v4[2] + v4[3]);
            }
        }
    }

    f32x4 oacc[4];
#pragma unroll
    for (int nt = 0; nt < 4; nt++) oacc[nt] = (f32x4){0.f, 0.f, 0.f, 0.f};

    for (int jt = 0; jt < 16; jt++) {
        const int j0 = jt * 64;
        f32x4 sc[4];
#pragma unroll
        for (int nt = 0; nt < 4; nt++) {
            f32x4 a = (f32x4){0.f, 0.f, 0.f, 0.f};
#pragma unroll
            for (int kc = 0; kc < 2; kc++) {
                u32x4 bfr = *(const u32x4*)(kh + (size_t)(j0 + nt * 16 + l15) * 64 + kc * 32 + quad * 8);
                a = mfma16(aq[kc], bfr, a);
            }
            sc[nt] = a;
        }
        __syncthreads();
#pragma unroll
        for (int nt = 0; nt < 4; nt++)
#pragma unroll
            for (int r = 0; r < 4; r++)
                SP[((quad * 4 + r) * 64 + nt * 16 + l15) * 18 + w] = f2bf(sc[nt][r] * 0.125f);
        __syncthreads();
#pragma unroll
        for (int t = 0; t < 6; t++) {
            const int s = w + 12 * t;
            if (s < 64) {
                const int row = s * 16 + l15, i = s >> 2, jq = s & 3;
                u32x4 bfr = (u32x4){0, 0, 0, 0};
                if (quad < 2) {
                    const u32* p = SP32 + row * 9 + quad * 4;
                    bfr[0] = p[0]; bfr[1] = p[1]; bfr[2] = p[2]; bfr[3] = p[3];
                }
                f32x4 d = mfma16(apre, bfr, (f32x4){0.f, 0.f, 0.f, 0.f});
                u16 p0 = f2bf(__expf(d[0]) * invl[t][0]);
                u16 p1 = f2bf(__expf(d[1]) * invl[t][1]);
                u16 p2 = f2bf(__expf(d[2]) * invl[t][2]);
                u16 p3 = f2bf(__expf(d[3]) * invl[t][3]);
                SP32[row * 9 + quad * 2]     = (u32)p0 | ((u32)p1 << 16);
                SP32[row * 9 + quad * 2 + 1] = (u32)p2 | ((u32)p3 << 16);
                __asm__ volatile("s_waitcnt lgkmcnt(0)" ::: "memory");
                u32x4 bfp = (u32x4){0, 0, 0, 0};
                if (quad < 2) {
                    const u32* p = SP32 + row * 9 + quad * 4;
                    bfp[0] = p[0]; bfp[1] = p[1]; bfp[2] = p[2]; bfp[3] = p[3];
                }
                f32x4 am = mfma16(apost, bfp, (f32x4){0.f, 0.f, 0.f, 0.f});
#pragma unroll
                for (int r = 0; r < 4; r++) {
                    const int g2 = quad * 4 + r;
                    if (g2 < 12)
                        Abuf[g2 * 1160 + i * 72 + jq * 16 + l15] = f2bf(am[r]);
                }
            }
        }
        __syncthreads();
#pragma unroll
        for (int kc = 0; kc < 2; kc++) {
            u32x4 af = *(const u32x4*)&Abuf[w * 1160 + l15 * 72 + kc * 32 + quad * 8];
#pragma unroll
            for (int nt = 0; nt < 4; nt++) {
                u32x4 vf = *(const u32x4*)(vh + (size_t)(nt * 16 + l15) * 1024 + j0 + kc * 32 + quad * 8);
                oacc[nt] = mfma16(af, vf, oacc[nt]);
            }
        }
    }
#pragma unroll
    for (int nt = 0; nt < 4; nt++)
#pragma unroll
        for (int r = 0; r < 4; r++)
            ob[((size_t)b * 1024 + i0 + quad * 4 + r) * 768 + w * 64 + nt * 16 + l15] =
                f2bf(oacc[nt][r]);
}

// =====================================================================
extern "C" void kernel_launch(void* const* d_in, const int* in_sizes, int n_in,
                              void* d_out, int out_size, void* d_ws, size_t ws_size,
                              hipStream_t stream)
{
    float* out = (float*)d_out;

    u32* flag = (u32*)d_ws;
    u16* WoT  = (u16*)d_ws + 128;            // 589,824 u16
    u16* qb   = WoT + 768 * 768;             // 6,291,456 each
    u16* kb   = qb  + 6291456;
    u16* vtb  = kb  + 6291456;
    u16* obuf = vtb + 6291456;               // aliases vb (v dead after transpose)
    u16* vb   = obuf;
    u16* ez   = obuf + 6291456;              // E zone; WT aliases it (dead before k_attn)
    u16* WT   = ez;
    u16* E    = ez;

    const size_t base   = 256 + 2ull * (768 * 768 + 4ull * 6291456);   // 51,511,552 B
    const size_t eslot  = 16384ull * 12 * 2;                           // 393,216 B per WG
    const size_t need1  = base + 512ull * eslot + 64;                  // 252.8 MB -> T=1
    const size_t need2  = base + 256ull * eslot + 64;                  // 152.2 MB -> T=2

    k_detect     <<<dim3(1), 64,  0, stream>>>((const u16*)d_in[0], flag);
    k_transpose_w<<<dim3(12, 24, 3), 256, 0, stream>>>(d_in[1], d_in[2], d_in[5], WT, WoT, flag);
    k_gemm_qkv   <<<dim3(36, 128),   256, 0, stream>>>(d_in[0], WT, qb, kb, vb, flag);
    k_transpose_v<<<dim3(16, 1, 96), 256, 0, stream>>>(vb, vtb);
    if (ws_size >= need1)
        k_attn   <<<dim3(64, 8), 768, 0, stream>>>(qb, kb, vtb, d_in[3], d_in[4], obuf, E, flag, 1);
    else if (ws_size >= need2)
        k_attn   <<<dim3(32, 8), 768, 0, stream>>>(qb, kb, vtb, d_in[3], d_in[4], obuf, E, flag, 2);
    else
        k_attn_fb<<<dim3(64, 8), 768, 0, stream>>>(qb, kb, vtb, d_in[3], d_in[4], obuf, flag);
    k_gemm_out   <<<dim3(12, 128),   256, 0, stream>>>(obuf, WoT, d_in[6], out, flag);
}

// Round 7
// 466.306 us; speedup vs baseline: 1.2411x; 1.1153x over previous
//
#include <hip/hip_runtime.h>
#include <cstdint>
#include <cstddef>

typedef unsigned short u16;
typedef unsigned int u32;

typedef __bf16 bf16x8 __attribute__((ext_vector_type(8)));
typedef float f32x4 __attribute__((ext_vector_type(4)));
typedef u32 u32x4 __attribute__((ext_vector_type(4)));
typedef u32 u32x2 __attribute__((ext_vector_type(2)));

#if defined(__has_builtin)
#if __has_builtin(__builtin_amdgcn_global_load_lds)
#define USE_GLL 1
#endif
#endif

typedef const __attribute__((address_space(1))) u32 gas_u32;
typedef __attribute__((address_space(3))) u32 las_u32;

__device__ inline float bf2f(u16 u) {
    union { u32 i; float f; } c; c.i = ((u32)u) << 16; return c.f;
}
__device__ inline u16 f2bf(float f) {
    union { float f; u32 i; } c; c.f = f;
    u32 u = c.i;
    return (u16)((u + 0x7fffu + ((u >> 16) & 1u)) >> 16);  // RNE
}
__device__ inline f32x4 mfma16(u32x4 a, u32x4 b, f32x4 c) {
    return __builtin_amdgcn_mfma_f32_16x16x32_bf16(
        __builtin_bit_cast(bf16x8, a), __builtin_bit_cast(bf16x8, b), c, 0, 0, 0);
}
__device__ inline u32x4 cvt8(const float* p) {
    f32x4 a = *(const f32x4*)p, b = *(const f32x4*)(p + 4);
    u32x4 v;
    v[0] = (u32)f2bf(a[0]) | ((u32)f2bf(a[1]) << 16);
    v[1] = (u32)f2bf(a[2]) | ((u32)f2bf(a[3]) << 16);
    v[2] = (u32)f2bf(b[0]) | ((u32)f2bf(b[1]) << 16);
    v[3] = (u32)f2bf(b[2]) | ((u32)f2bf(b[3]) << 16);
    return v;
}

// ===================== dtype detector (round-1 forensics: inputs fp32) ========
__global__ __launch_bounds__(64) void k_detect(const u16* __restrict__ x, u32* __restrict__ flag)
{
    const int lane = threadIdx.x;
    int cnt = 0;
#pragma unroll
    for (int i = 0; i < 4; i++) {
        u32 e = (x[lane * 4 + i] >> 7) & 0xFF;
        cnt += (e >= 115 && e <= 133) ? 1 : 0;
    }
#pragma unroll
    for (int off = 1; off < 64; off <<= 1) cnt += __shfl_xor(cnt, off);
    if (lane == 0) *flag = (cnt >= 192) ? 1u : 0u;
}

// ===================== X -> bf16 convert (one-shot; copy if already bf16) =====
__global__ __launch_bounds__(256) void k_convert_x(
    const void* __restrict__ X, u16* __restrict__ xb, const u32* __restrict__ flag)
{
    const bool isb = (*flag != 0);
    const size_t i = ((size_t)blockIdx.x * 256 + threadIdx.x) * 8;
    if (isb) *(u32x4*)(xb + i) = *(const u32x4*)((const u16*)X + i);
    else     *(u32x4*)(xb + i) = cvt8((const float*)X + i);
}

// ===================== weight transpose (unchanged, validated) ================
__global__ __launch_bounds__(256) void k_transpose_w(
    const void* __restrict__ Wq, const void* __restrict__ Wkv, const void* __restrict__ Wo,
    u16* __restrict__ WT, u16* __restrict__ WoT, const u32* __restrict__ flag)
{
    const bool isb = (*flag != 0);
    __shared__ __align__(16) u16 t[64][72];
    const int z = blockIdx.z;
    const void* src; u16* dst; int C;
    if (z == 0)      { src = Wq;  dst = WT;             C = 768;  }
    else if (z == 1) { src = Wkv; dst = WT + 768 * 768; C = 1536; }
    else             { src = Wo;  dst = WoT;            C = 768;  }
    const int c0 = blockIdx.y * 64;
    if (c0 >= C) return;
    const int k0 = blockIdx.x * 64;
    const int tid = threadIdx.x;
    const int r = tid >> 3, cc = (tid & 7) * 8;
    if (isb) {
        const u16* s = (const u16*)src;
        for (int rr = r; rr < 64; rr += 32)
            *(u32x4*)&t[rr][cc] = *(const u32x4*)(s + (size_t)(k0 + rr) * C + c0 + cc);
    } else {
        const float* s = (const float*)src;
        for (int rr = r; rr < 64; rr += 32)
            *(u32x4*)&t[rr][cc] = cvt8(s + (size_t)(k0 + rr) * C + c0 + cc);
    }
    __syncthreads();
    const int kk = (tid & 7) * 8;
    for (int ccc = tid >> 3; ccc < 64; ccc += 32) {
        __align__(16) u16 tmp[8];
#pragma unroll
        for (int s = 0; s < 8; s++) tmp[s] = t[kk + s][ccc];
        *(u32x4*)(dst + (size_t)(c0 + ccc) * 768 + k0 + kk) = *(u32x4*)tmp;
    }
}

// ===================== v transpose (unchanged, validated) =====================
__global__ __launch_bounds__(256) void k_transpose_v(
    const u16* __restrict__ v, u16* __restrict__ vt)
{
    __shared__ __align__(16) u16 t[64][72];
    const int bh = blockIdx.z;
    const int t0 = blockIdx.x * 64;
    const int tid = threadIdx.x;
    const int r = tid >> 3, cc = (tid & 7) * 8;
    for (int rr = r; rr < 64; rr += 32)
        *(u32x4*)&t[rr][cc] = *(const u32x4*)(v + ((size_t)bh * 1024 + t0 + rr) * 64 + cc);
    __syncthreads();
    const int kk = (tid & 7) * 8;
    for (int ccc = tid >> 3; ccc < 64; ccc += 32) {
        __align__(16) u16 tmp[8];
#pragma unroll
        for (int s = 0; s < 8; s++) tmp[s] = t[kk + s][ccc];
        *(u32x4*)(vt + ((size_t)bh * 64 + ccc) * 1024 + t0 + kk) = *(u32x4*)tmp;
    }
}

// ---- shared staging helper for the 128x128 m97-style GEMMs -------------------
// As/Bs: row-major [128][32] bf16 (no pad; layout fixed by global_load_lds).
__device__ inline void stage_tile(const u16* __restrict__ gA, const u16* __restrict__ gB,
                                  u16* As, u16* Bs, int w, int lane)
{
    const int sr = lane >> 2, sc = (lane & 3) * 8;
#pragma unroll
    for (int i = 0; i < 2; i++) {
        const int rA = w * 16 + i * 64;
        const u16* ga = gA + (size_t)(rA + sr) * 768 + sc;
        const u16* gb = gB + (size_t)(rA + sr) * 768 + sc;
#ifdef USE_GLL
        __builtin_amdgcn_global_load_lds((gas_u32*)ga, (las_u32*)&As[rA * 32], 16, 0, 0);
        __builtin_amdgcn_global_load_lds((gas_u32*)gb, (las_u32*)&Bs[rA * 32], 16, 0, 0);
#else
        *(u32x4*)&As[(rA + sr) * 32 + sc] = *(const u32x4*)ga;
        *(u32x4*)&Bs[(rA + sr) * 32 + sc] = *(const u32x4*)gb;
#endif
    }
}

// ===================== QKV GEMM v2: 128x128 tile, global_load_lds =============
// xb[8192,768] bf16 @ WT^T(2304x768) -> q,k,v [B,H,N,DH].  grid (18,64).
__global__ __launch_bounds__(256) void k_gemm_qkv(
    const u16* __restrict__ Xb, const u16* __restrict__ WT,
    u16* __restrict__ qb, u16* __restrict__ kb, u16* __restrict__ vb)
{
    __shared__ __align__(16) u16 As[128 * 32];
    __shared__ __align__(16) u16 Bs[128 * 32];
    const int tid = threadIdx.x;
    const int w = tid >> 6, lane = tid & 63, quad = lane >> 4, l15 = lane & 15;
    const int wr = w >> 1, wc = w & 1;
    const int m0 = blockIdx.y * 128, c0 = blockIdx.x * 128;
    f32x4 acc[4][4];
#pragma unroll
    for (int i = 0; i < 4; i++)
#pragma unroll
        for (int j = 0; j < 4; j++) acc[i][j] = (f32x4){0.f, 0.f, 0.f, 0.f};

    for (int k0 = 0; k0 < 768; k0 += 32) {
        __syncthreads();                       // prior frag reads done
        stage_tile(Xb + (size_t)m0 * 768 + k0, WT + (size_t)c0 * 768 + k0, As, Bs, w, lane);
        __syncthreads();                       // staged visible (drains vmcnt)
        u32x4 af[4], bfv[4];
#pragma unroll
        for (int mi = 0; mi < 4; mi++)
            af[mi] = *(const u32x4*)&As[(wr * 64 + mi * 16 + l15) * 32 + quad * 8];
#pragma unroll
        for (int ni = 0; ni < 4; ni++)
            bfv[ni] = *(const u32x4*)&Bs[(wc * 64 + ni * 16 + l15) * 32 + quad * 8];
#pragma unroll
        for (int mi = 0; mi < 4; mi++)
#pragma unroll
            for (int ni = 0; ni < 4; ni++)
                acc[mi][ni] = mfma16(af[mi], bfv[ni], acc[mi][ni]);
    }
#pragma unroll
    for (int mi = 0; mi < 4; mi++)
#pragma unroll
        for (int ni = 0; ni < 4; ni++) {
            const int c = c0 + wc * 64 + ni * 16 + l15;
            const int sector = c / 768, hc = c % 768;
            const int h = hc >> 6, d = hc & 63;
            u16* dst = sector == 0 ? qb : (sector == 1 ? kb : vb);
#pragma unroll
            for (int r = 0; r < 4; r++) {
                const int tok = m0 + wr * 64 + mi * 16 + quad * 4 + r;
                const int b = tok >> 10, n = tok & 1023;
                dst[(((size_t)b * 12 + h) * 1024 + n) * 64 + d] = f2bf(acc[mi][ni][r]);
            }
        }
}

// ===================== output GEMM v2: 128x128 tile, fp32 out ================
__global__ __launch_bounds__(256) void k_gemm_out(
    const u16* __restrict__ O, const u16* __restrict__ WoT, const void* __restrict__ bo,
    float* __restrict__ out, const u32* __restrict__ flag)
{
    const bool isb = (*flag != 0);
    __shared__ __align__(16) u16 As[128 * 32];
    __shared__ __align__(16) u16 Bs[128 * 32];
    const int tid = threadIdx.x;
    const int w = tid >> 6, lane = tid & 63, quad = lane >> 4, l15 = lane & 15;
    const int wr = w >> 1, wc = w & 1;
    const int m0 = blockIdx.y * 128, c0 = blockIdx.x * 128;
    f32x4 acc[4][4];
#pragma unroll
    for (int i = 0; i < 4; i++)
#pragma unroll
        for (int j = 0; j < 4; j++) acc[i][j] = (f32x4){0.f, 0.f, 0.f, 0.f};

    for (int k0 = 0; k0 < 768; k0 += 32) {
        __syncthreads();
        stage_tile(O + (size_t)m0 * 768 + k0, WoT + (size_t)c0 * 768 + k0, As, Bs, w, lane);
        __syncthreads();
        u32x4 af[4], bfv[4];
#pragma unroll
        for (int mi = 0; mi < 4; mi++)
            af[mi] = *(const u32x4*)&As[(wr * 64 + mi * 16 + l15) * 32 + quad * 8];
#pragma unroll
        for (int ni = 0; ni < 4; ni++)
            bfv[ni] = *(const u32x4*)&Bs[(wc * 64 + ni * 16 + l15) * 32 + quad * 8];
#pragma unroll
        for (int mi = 0; mi < 4; mi++)
#pragma unroll
            for (int ni = 0; ni < 4; ni++)
                acc[mi][ni] = mfma16(af[mi], bfv[ni], acc[mi][ni]);
    }
#pragma unroll
    for (int mi = 0; mi < 4; mi++)
#pragma unroll
        for (int ni = 0; ni < 4; ni++) {
            const int c = c0 + wc * 64 + ni * 16 + l15;
            const float biasv = isb ? bf2f(((const u16*)bo)[c]) : ((const float*)bo)[c];
#pragma unroll
            for (int r = 0; r < 4; r++) {
                const int tok = m0 + wr * 64 + mi * 16 + quad * 4 + r;
                out[(size_t)tok * 768 + c] = acc[mi][ni][r] + biasv;
            }
        }
}

// =====================================================================
// k_attn v4.1: E-spill talking-heads attention (round-6 validated) with
// XCD-aware 1-D grid: b = bid&7 so each XCD's L2 holds one batch's K/V.
// =====================================================================
__global__ __launch_bounds__(768) void k_attn(
    const u16* __restrict__ qb, const u16* __restrict__ kb, const u16* __restrict__ vt,
    const void* __restrict__ mixpre, const void* __restrict__ mixpost,
    u16* __restrict__ ob, u16* __restrict__ E, const u32* __restrict__ flag, int tiles)
{
    __shared__ __align__(16) u16 LDSU[18432];      // 36,864 B union: SP (p1) / Abuf (p2)
    __shared__ float invlT[256];                   // [i][h] 16x16 f32
    u16* SP   = LDSU;
    u32* SP32 = (u32*)LDSU;
    u16* Abuf = LDSU;
    float* red = (float*)LDSU;

    const bool isb = (*flag != 0);
    const int tid = threadIdx.x;
    const int w = tid >> 6, lane = tid & 63, quad = lane >> 4, l15 = lane & 15;
    const int bid = blockIdx.x;
    const int b = bid & 7;                         // XCD-aware: batch per XCD
    const int nq = gridDim.x >> 3;
    u16* Ewg = E + (size_t)bid * (16384 * 12);

    u32x4 apre = (u32x4){0, 0, 0, 0};
    float mpostF[8];
#pragma unroll
    for (int j = 0; j < 8; j++) {
        const int h = quad * 8 + j;
        mpostF[j] = 0.f;
        if (quad < 2 && l15 < 12 && h < 12) {
            mpostF[j] = isb ? bf2f(((const u16*)mixpost)[h * 12 + l15])
                            : ((const float*)mixpost)[h * 12 + l15];
            u16 v1 = isb ? ((const u16*)mixpre)[h * 12 + l15]
                         : f2bf(((const float*)mixpre)[h * 12 + l15]);
            apre[j >> 1] |= ((u32)v1) << ((j & 1) * 16);
        }
    }

    const u16* kh = kb + ((size_t)b * 12 + w) * 1024 * 64;
    const u16* vh = vt + ((size_t)b * 12 + w) * 64 * 1024;

    for (int tt = 0; tt < tiles; tt++) {
        const int qx = (bid >> 3) + tt * nq;
        const int i0 = qx * 16;

        for (int n = tid; n < 1024; n += 768) { SP32[n * 9 + 6] = 0; SP32[n * 9 + 7] = 0; }

        const u16* qh = qb + (((size_t)b * 12 + w) * 1024 + i0) * 64;
        u32x4 aq[2];
#pragma unroll
        for (int kc = 0; kc < 2; kc++)
            aq[kc] = *(const u32x4*)(qh + l15 * 64 + kc * 32 + quad * 8);

        // ---------------- pass 1: QK^T -> premix -> exp -> E + row sums ------
        f32x4 part[6];
#pragma unroll
        for (int t = 0; t < 6; t++) part[t] = (f32x4){0.f, 0.f, 0.f, 0.f};

        for (int jt = 0; jt < 16; jt++) {
            const int j0 = jt * 64;
            f32x4 sc[4];
#pragma unroll
            for (int nt = 0; nt < 4; nt++) {
                f32x4 a = (f32x4){0.f, 0.f, 0.f, 0.f};
#pragma unroll
                for (int kc = 0; kc < 2; kc++) {
                    u32x4 bfr = *(const u32x4*)(kh + (size_t)(j0 + nt * 16 + l15) * 64 + kc * 32 + quad * 8);
                    a = mfma16(aq[kc], bfr, a);
                }
                sc[nt] = a;
            }
            __syncthreads();
#pragma unroll
            for (int nt = 0; nt < 4; nt++)
#pragma unroll
                for (int r = 0; r < 4; r++)
                    SP[((quad * 4 + r) * 64 + nt * 16 + l15) * 18 + w] = f2bf(sc[nt][r] * 0.125f);
            __syncthreads();
#pragma unroll
            for (int t = 0; t < 6; t++) {
                const int s = w + 12 * t;
                if (s < 64) {
                    const int row = s * 16 + l15;
                    u32x4 bfr = (u32x4){0, 0, 0, 0};
                    if (quad < 2) {
                        const u32* p = SP32 + row * 9 + quad * 4;
                        bfr[0] = p[0]; bfr[1] = p[1]; bfr[2] = p[2]; bfr[3] = p[3];
                    }
                    f32x4 d = mfma16(apre, bfr, (f32x4){0.f, 0.f, 0.f, 0.f});
                    const float e0 = __expf(d[0]), e1 = __expf(d[1]);
                    const float e2 = __expf(d[2]), e3 = __expf(d[3]);
                    part[t][0] += e0; part[t][1] += e1;
                    part[t][2] += e2; part[t][3] += e3;
                    if (quad < 3) {
                        u32x2 pk;
                        pk[0] = (u32)f2bf(e0) | ((u32)f2bf(e1) << 16);
                        pk[1] = (u32)f2bf(e2) | ((u32)f2bf(e3) << 16);
                        *(u32x2*)(Ewg + ((size_t)jt * 1024 + row) * 12 + quad * 4) = pk;
                    }
                }
            }
        }
        __syncthreads();
#pragma unroll
        for (int t = 0; t < 6; t++) {
            const int s = w + 12 * t;
            if (s < 64) {
#pragma unroll
                for (int r = 0; r < 4; r++) {
                    float v = part[t][r];
#pragma unroll
                    for (int off = 1; off < 16; off <<= 1) v += __shfl_xor(v, off);
                    if (l15 == 0) red[(((s >> 2) * 16) + quad * 4 + r) * 4 + (s & 3)] = v;
                }
            }
        }
        __syncthreads();
        if (tid < 256) {
            const int h = tid & 15;
            float v = 0.f;
            if (h < 12) {
                const float* q = &red[tid * 4];
                v = 1.f / (q[0] + q[1] + q[2] + q[3]);
            }
            invlT[tid] = v;
        }
        __syncthreads();

        u32x4 Afr[6];
#pragma unroll
        for (int t = 0; t < 6; t++) {
            const int s = w + 12 * t;
            Afr[t] = (u32x4){0, 0, 0, 0};
            if (s < 64 && quad < 2) {
                const int i = s >> 2;
#pragma unroll
                for (int j = 0; j < 8; j++) {
                    const u16 v = f2bf(mpostF[j] * invlT[i * 16 + quad * 8 + j]);
                    Afr[t][j >> 1] |= ((u32)v) << ((j & 1) * 16);
                }
            }
        }

        // ---------------- pass 2: reload E -> postmix -> PV ------------------
        f32x4 oacc[4];
#pragma unroll
        for (int nt = 0; nt < 4; nt++) oacc[nt] = (f32x4){0.f, 0.f, 0.f, 0.f};

        for (int jt = 0; jt < 16; jt++) {
            const int j0 = jt * 64;
#pragma unroll
            for (int t = 0; t < 6; t++) {
                const int s = w + 12 * t;
                if (s < 64) {
                    const int row = s * 16 + l15, i = s >> 2, jq = s & 3;
                    u32x4 ef = (u32x4){0, 0, 0, 0};
                    if (quad < 2) {
                        const u16* ep = Ewg + ((size_t)jt * 1024 + row) * 12 + quad * 8;
                        u32x2 lo = *(const u32x2*)ep;
                        u32x2 hi = *(const u32x2*)(ep + 4);
                        ef[0] = lo[0]; ef[1] = lo[1]; ef[2] = hi[0]; ef[3] = hi[1];
                    }
                    f32x4 am = mfma16(Afr[t], ef, (f32x4){0.f, 0.f, 0.f, 0.f});
#pragma unroll
                    for (int r = 0; r < 4; r++) {
                        const int g2 = quad * 4 + r;
                        if (g2 < 12)
                            Abuf[g2 * 1160 + i * 72 + jq * 16 + l15] = f2bf(am[r]);
                    }
                }
            }
            __syncthreads();
#pragma unroll
            for (int kc = 0; kc < 2; kc++) {
                u32x4 af = *(const u32x4*)&Abuf[w * 1160 + l15 * 72 + kc * 32 + quad * 8];
#pragma unroll
                for (int nt = 0; nt < 4; nt++) {
                    u32x4 vf = *(const u32x4*)(vh + (size_t)(nt * 16 + l15) * 1024 + j0 + kc * 32 + quad * 8);
                    oacc[nt] = mfma16(af, vf, oacc[nt]);
                }
            }
            __syncthreads();
        }
#pragma unroll
        for (int nt = 0; nt < 4; nt++)
#pragma unroll
            for (int r = 0; r < 4; r++)
                ob[((size_t)b * 1024 + i0 + quad * 4 + r) * 768 + w * 64 + nt * 16 + l15] =
                    f2bf(oacc[nt][r]);
    }
}

// =====================================================================
extern "C" void kernel_launch(void* const* d_in, const int* in_sizes, int n_in,
                              void* d_out, int out_size, void* d_ws, size_t ws_size,
                              hipStream_t stream)
{
    float* out = (float*)d_out;

    u32* flag = (u32*)d_ws;
    u16* WoT  = (u16*)d_ws + 128;            // 589,824 u16
    u16* qb   = WoT + 768 * 768;             // 6,291,456 each
    u16* kb   = qb  + 6291456;
    u16* vtb  = kb  + 6291456;
    u16* obuf = vtb + 6291456;               // aliases vb (v dead after transpose)
    u16* vb   = obuf;
    u16* ez   = obuf + 6291456;              // E zone; WT+xb alias it (dead before k_attn)
    u16* WT   = ez;                          // 1,769,472 u16
    u16* xb   = ez + 2304 * 768;             // 6,291,456 u16 bf16 X
    u16* E    = ez;

    const size_t base   = 256 + 2ull * (768 * 768 + 4ull * 6291456);   // 51.5 MB
    const size_t eslot  = 16384ull * 12 * 2;                           // 393,216 B per WG
    const size_t need1  = base + 512ull * eslot + 64;                  // ~252.8 MB -> T=1
    const size_t need2  = base + 256ull * eslot + 64;                  // ~152.2 MB -> T=2

    k_detect     <<<dim3(1), 64,  0, stream>>>((const u16*)d_in[0], flag);
    k_transpose_w<<<dim3(12, 24, 3), 256, 0, stream>>>(d_in[1], d_in[2], d_in[5], WT, WoT, flag);
    k_convert_x  <<<dim3(3072),      256, 0, stream>>>(d_in[0], xb, flag);
    k_gemm_qkv   <<<dim3(18, 64),    256, 0, stream>>>(xb, WT, qb, kb, vb);
    k_transpose_v<<<dim3(16, 1, 96), 256, 0, stream>>>(vb, vtb);
    if (ws_size >= need1)
        k_attn   <<<dim3(512), 768, 0, stream>>>(qb, kb, vtb, d_in[3], d_in[4], obuf, E, flag, 1);
    else
        k_attn   <<<dim3(256), 768, 0, stream>>>(qb, kb, vtb, d_in[3], d_in[4], obuf, E, flag, 2);
    k_gemm_out   <<<dim3(6, 64),     256, 0, stream>>>(obuf, WoT, d_in[6], out, flag);
}